// Round 1
// baseline (2240.484 us; speedup 1.0000x reference)
//
#include <hip/hip_runtime.h>

#define NN 100000
#define EE 1600000
#define TOT (EE + NN)

static __device__ inline void atomAddF(float* p, float v) {
    __hip_atomic_fetch_add(p, v, __ATOMIC_RELAXED, __HIP_MEMORY_SCOPE_AGENT);
}

// ---------------- copy logits into x[:, :40] ----------------
__global__ void copy_logits_kernel(const float* __restrict__ logits, float* __restrict__ x) {
    int idx = blockIdx.x * blockDim.x + threadIdx.x;
    if (idx < NN * 40) {
        int n = idx / 40, c = idx - n * 40;
        x[n * 168 + c] = logits[idx];
    }
}

// ---------------- generic tiled f32 GEMM: C[M,N] = A[M,K]@B[K,N] (+bias) ----------------
template <int RELU>
__global__ void gemm_kernel(const float* __restrict__ A, int lda,
                            const float* __restrict__ B, int ldb,
                            float* __restrict__ C, int ldc,
                            const float* __restrict__ bias,
                            int M, int N, int K) {
    __shared__ float As[64][17];
    __shared__ float Bs[16][65];
    int tid = threadIdx.x;
    int tx = tid & 15, ty = tid >> 4;
    int row0 = blockIdx.y * 64;
    int col0 = blockIdx.x * 64;
    float acc[4][4] = {};
    for (int k0 = 0; k0 < K; k0 += 16) {
#pragma unroll
        for (int i = 0; i < 4; ++i) {
            int idx = tid + i * 256;
            int r = idx >> 4, c = idx & 15;
            int gr = row0 + r, gc = k0 + c;
            As[r][c] = (gr < M && gc < K) ? A[(long long)gr * lda + gc] : 0.f;
        }
#pragma unroll
        for (int i = 0; i < 4; ++i) {
            int idx = tid + i * 256;
            int r = idx >> 6, c = idx & 63;
            int gr = k0 + r, gc = col0 + c;
            Bs[r][c] = (gr < K && gc < N) ? B[gr * ldb + gc] : 0.f;
        }
        __syncthreads();
#pragma unroll
        for (int kk = 0; kk < 16; ++kk) {
            float a[4], b[4];
#pragma unroll
            for (int i = 0; i < 4; ++i) a[i] = As[ty * 4 + i][kk];
#pragma unroll
            for (int j = 0; j < 4; ++j) b[j] = Bs[kk][tx * 4 + j];
#pragma unroll
            for (int i = 0; i < 4; ++i)
#pragma unroll
                for (int j = 0; j < 4; ++j) acc[i][j] += a[i] * b[j];
        }
        __syncthreads();
    }
#pragma unroll
    for (int i = 0; i < 4; ++i) {
        int r = row0 + ty * 4 + i;
        if (r >= M) continue;
#pragma unroll
        for (int j = 0; j < 4; ++j) {
            int c = col0 + tx * 4 + j;
            if (c >= N) continue;
            float v = acc[i][j] + (bias ? bias[c] : 0.f);
            if (RELU) v = fmaxf(v, 0.f);
            C[(long long)r * ldc + c] = v;
        }
    }
}

// ---------------- per-node attention coefficients ----------------
// one wave (64 lanes) per (node, head): a_src[n,h] = dot(hbuf[n,h,:], att_src[h,:])
__global__ void attn_coef_kernel(const float* __restrict__ hbuf,
                                 const float* __restrict__ att_src,
                                 const float* __restrict__ att_dst,
                                 float* __restrict__ a_src,
                                 float* __restrict__ a_dst) {
    int gw = (blockIdx.x * blockDim.x + threadIdx.x) >> 6;
    int lane = threadIdx.x & 63;
    if (gw >= NN * 2) return;
    int n = gw >> 1, head = gw & 1;
    float hv = hbuf[n * 128 + head * 64 + lane];
    float vs = hv * att_src[head * 64 + lane];
    float vd = hv * att_dst[head * 64 + lane];
#pragma unroll
    for (int off = 32; off; off >>= 1) {
        vs += __shfl_down(vs, off);
        vd += __shfl_down(vd, off);
    }
    if (lane == 0) {
        a_src[n * 2 + head] = vs;
        a_dst[n * 2 + head] = vd;
    }
}

// ---------------- softmax denominator: denom[dst,h] += exp(leaky(e)) ----------------
__global__ void edge_denom_kernel(const int* __restrict__ ei,
                                  const float* __restrict__ a_src,
                                  const float* __restrict__ a_dst,
                                  float* __restrict__ denom) {
    long long idx = (long long)blockIdx.x * blockDim.x + threadIdx.x;
    if (idx >= (long long)TOT * 2) return;
    int e = (int)(idx >> 1), head = (int)(idx & 1);
    int s, d;
    if (e < EE) { s = ei[e]; d = ei[EE + e]; }
    else { s = e - EE; d = s; }
    float v = a_src[s * 2 + head] + a_dst[d * 2 + head];
    v = v > 0.f ? v : 0.2f * v;
    atomAddF(&denom[d * 2 + head], expf(v));
}

// ---------------- weighted aggregation: out[dst,c] += alpha * h[src,c] ----------------
// 256 threads = 2 edges x 128 channels
__global__ void edge_agg_kernel(const int* __restrict__ ei,
                                const float* __restrict__ a_src,
                                const float* __restrict__ a_dst,
                                const float* __restrict__ denom,
                                const float* __restrict__ hbuf,
                                float* __restrict__ out) {
    long long idx = (long long)blockIdx.x * 256 + threadIdx.x;
    int e = (int)(idx >> 7);
    if (e >= TOT) return;
    int c = (int)(idx & 127);
    int head = c >> 6;
    int s, d;
    if (e < EE) { s = ei[e]; d = ei[EE + e]; }
    else { s = e - EE; d = s; }
    float v = a_src[s * 2 + head] + a_dst[d * 2 + head];
    v = v > 0.f ? v : 0.2f * v;
    float alpha = expf(v) / (denom[d * 2 + head] + 1e-16f);
    atomAddF(&out[d * 128 + c], alpha * hbuf[s * 128 + c]);
}

// ---------------- init accumulator with bias broadcast ----------------
__global__ void init_bias_kernel(float* __restrict__ out, const float* __restrict__ bias) {
    int idx = blockIdx.x * blockDim.x + threadIdx.x;
    if (idx < NN * 128) out[idx] = bias[idx & 127];
}

__global__ void relu_kernel(float* __restrict__ x, int total) {
    int idx = blockIdx.x * blockDim.x + threadIdx.x;
    if (idx < total) x[idx] = fmaxf(x[idx], 0.f);
}

extern "C" void kernel_launch(void* const* d_in, const int* in_sizes, int n_in,
                              void* d_out, int out_size, void* d_ws, size_t ws_size,
                              hipStream_t stream) {
    const float* logits   = (const float*)d_in[0];
    const float* features = (const float*)d_in[1];
    const int*   ei       = (const int*)d_in[2];
    const float* W_feat   = (const float*)d_in[3];
    const float* b_feat   = (const float*)d_in[4];
    const float* W0       = (const float*)d_in[5];
    const float* att_src0 = (const float*)d_in[6];
    const float* att_dst0 = (const float*)d_in[7];
    const float* bias0    = (const float*)d_in[8];
    const float* W1       = (const float*)d_in[9];
    const float* att_src1 = (const float*)d_in[10];
    const float* att_dst1 = (const float*)d_in[11];
    const float* bias1    = (const float*)d_in[12];
    const float* W_out    = (const float*)d_in[13];
    const float* b_out    = (const float*)d_in[14];
    float* out = (float*)d_out;

    float* x0    = (float*)d_ws;          // N*168
    float* hbuf  = x0 + (size_t)NN * 168; // N*128
    float* agg   = hbuf + (size_t)NN * 128; // N*128
    float* a_src = agg + (size_t)NN * 128;  // N*2
    float* a_dst = a_src + (size_t)NN * 2;  // N*2
    float* denom = a_dst + (size_t)NN * 2;  // N*2

    dim3 blk(256);

    // --- input assembly ---
    copy_logits_kernel<<<dim3((NN * 40 + 255) / 256), blk, 0, stream>>>(logits, x0);
    {
        dim3 grid((128 + 63) / 64, (NN + 63) / 64);
        gemm_kernel<0><<<grid, blk, 0, stream>>>(features, 256, W_feat, 128, x0 + 40, 168,
                                                 b_feat, NN, 128, 256);
    }

    int nEdgeThreads = TOT * 2;
    int nAggBlocks = (TOT + 1) / 2;

    // --- GAT layer 0 ---
    {
        dim3 grid((128 + 63) / 64, (NN + 63) / 64);
        gemm_kernel<0><<<grid, blk, 0, stream>>>(x0, 168, W0, 128, hbuf, 128,
                                                 (const float*)nullptr, NN, 128, 168);
    }
    attn_coef_kernel<<<dim3((NN * 2 * 64 + 255) / 256), blk, 0, stream>>>(hbuf, att_src0, att_dst0, a_src, a_dst);
    hipMemsetAsync(denom, 0, (size_t)NN * 2 * sizeof(float), stream);
    edge_denom_kernel<<<dim3((nEdgeThreads + 255) / 256), blk, 0, stream>>>(ei, a_src, a_dst, denom);
    init_bias_kernel<<<dim3((NN * 128 + 255) / 256), blk, 0, stream>>>(agg, bias0);
    edge_agg_kernel<<<dim3(nAggBlocks), blk, 0, stream>>>(ei, a_src, a_dst, denom, hbuf, agg);
    relu_kernel<<<dim3((NN * 128 + 255) / 256), blk, 0, stream>>>(agg, NN * 128);

    // --- GAT layer 1 ---
    {
        dim3 grid((128 + 63) / 64, (NN + 63) / 64);
        gemm_kernel<0><<<grid, blk, 0, stream>>>(agg, 128, W1, 128, hbuf, 128,
                                                 (const float*)nullptr, NN, 128, 128);
    }
    attn_coef_kernel<<<dim3((NN * 2 * 64 + 255) / 256), blk, 0, stream>>>(hbuf, att_src1, att_dst1, a_src, a_dst);
    hipMemsetAsync(denom, 0, (size_t)NN * 2 * sizeof(float), stream);
    edge_denom_kernel<<<dim3((nEdgeThreads + 255) / 256), blk, 0, stream>>>(ei, a_src, a_dst, denom);
    init_bias_kernel<<<dim3((NN * 128 + 255) / 256), blk, 0, stream>>>(agg, bias1);
    edge_agg_kernel<<<dim3(nAggBlocks), blk, 0, stream>>>(ei, a_src, a_dst, denom, hbuf, agg);

    // --- output projection ---
    {
        dim3 grid((40 + 63) / 64, (NN + 63) / 64);
        gemm_kernel<0><<<grid, blk, 0, stream>>>(agg, 128, W_out, 40, out, 40,
                                                 b_out, NN, 40, 128);
    }
}

// Round 2
// 1106.408 us; speedup vs baseline: 2.0250x; 2.0250x over previous
//
#include <hip/hip_runtime.h>

#define NN 100000
#define EE 1600000
#define NB_SCAN ((NN + 1023) / 1024)

// ================= CSR build =================
__global__ void hist_kernel(const int* __restrict__ ei, int* __restrict__ deg) {
    int e = blockIdx.x * blockDim.x + threadIdx.x;
    if (e < EE) atomicAdd(&deg[ei[EE + e]], 1);
}

__global__ void scan_block_sums(const int* __restrict__ deg, int* __restrict__ bsum) {
    __shared__ int sdata[256];
    int base = blockIdx.x * 1024;
    int t = threadIdx.x;
    int s = 0;
#pragma unroll
    for (int i = 0; i < 4; ++i) {
        int idx = base + t * 4 + i;
        if (idx < NN) s += deg[idx];
    }
    sdata[t] = s;
    __syncthreads();
    for (int off = 128; off; off >>= 1) {
        if (t < off) sdata[t] += sdata[t + off];
        __syncthreads();
    }
    if (t == 0) bsum[blockIdx.x] = sdata[0];
}

__global__ void scan_bsum_kernel(int* __restrict__ bsum, int nb) {
    if (threadIdx.x == 0 && blockIdx.x == 0) {
        int acc = 0;
        for (int i = 0; i < nb; ++i) { int v = bsum[i]; bsum[i] = acc; acc += v; }
    }
}

__global__ void scan_final_kernel(const int* __restrict__ deg, const int* __restrict__ bsum,
                                  int* __restrict__ row_ptr, int* __restrict__ cursor) {
    __shared__ int ssum[256];
    int base = blockIdx.x * 1024;
    int t = threadIdx.x;
    int loc[4];
    int s = 0;
#pragma unroll
    for (int i = 0; i < 4; ++i) {
        int idx = base + t * 4 + i;
        loc[i] = (idx < NN) ? deg[idx] : 0;
        s += loc[i];
    }
    ssum[t] = s;
    __syncthreads();
    // inclusive Hillis-Steele scan
    for (int off = 1; off < 256; off <<= 1) {
        int v = (t >= off) ? ssum[t - off] : 0;
        __syncthreads();
        ssum[t] += v;
        __syncthreads();
    }
    int excl = ssum[t] - s + bsum[blockIdx.x];
#pragma unroll
    for (int i = 0; i < 4; ++i) {
        int idx = base + t * 4 + i;
        if (idx < NN) {
            row_ptr[idx] = excl;
            cursor[idx] = excl;
            excl += loc[i];
        }
    }
    if (blockIdx.x == 0 && t == 0) row_ptr[NN] = EE;
}

__global__ void scatter_kernel(const int* __restrict__ ei, int* __restrict__ cursor,
                               int* __restrict__ col) {
    int e = blockIdx.x * blockDim.x + threadIdx.x;
    if (e < EE) {
        int d = ei[EE + e];
        int pos = atomicAdd(&cursor[d], 1);
        col[pos] = ei[e];
    }
}

// ================= dense pieces =================
__global__ void copy_logits_kernel(const float* __restrict__ logits, float* __restrict__ x) {
    int idx = blockIdx.x * blockDim.x + threadIdx.x;
    if (idx < NN * 40) {
        int n = idx / 40, c = idx - n * 40;
        x[n * 168 + c] = logits[idx];
    }
}

template <int RELU>
__global__ void gemm_kernel(const float* __restrict__ A, int lda,
                            const float* __restrict__ B, int ldb,
                            float* __restrict__ C, int ldc,
                            const float* __restrict__ bias,
                            int M, int N, int K) {
    __shared__ float As[64][17];
    __shared__ float Bs[16][65];
    int tid = threadIdx.x;
    int tx = tid & 15, ty = tid >> 4;
    int row0 = blockIdx.y * 64;
    int col0 = blockIdx.x * 64;
    float acc[4][4] = {};
    for (int k0 = 0; k0 < K; k0 += 16) {
#pragma unroll
        for (int i = 0; i < 4; ++i) {
            int idx = tid + i * 256;
            int r = idx >> 4, c = idx & 15;
            int gr = row0 + r, gc = k0 + c;
            As[r][c] = (gr < M && gc < K) ? A[(long long)gr * lda + gc] : 0.f;
        }
#pragma unroll
        for (int i = 0; i < 4; ++i) {
            int idx = tid + i * 256;
            int r = idx >> 6, c = idx & 63;
            int gr = k0 + r, gc = col0 + c;
            Bs[r][c] = (gr < K && gc < N) ? B[gr * ldb + gc] : 0.f;
        }
        __syncthreads();
#pragma unroll
        for (int kk = 0; kk < 16; ++kk) {
            float a[4], b[4];
#pragma unroll
            for (int i = 0; i < 4; ++i) a[i] = As[ty * 4 + i][kk];
#pragma unroll
            for (int j = 0; j < 4; ++j) b[j] = Bs[kk][tx * 4 + j];
#pragma unroll
            for (int i = 0; i < 4; ++i)
#pragma unroll
                for (int j = 0; j < 4; ++j) acc[i][j] += a[i] * b[j];
        }
        __syncthreads();
    }
#pragma unroll
    for (int i = 0; i < 4; ++i) {
        int r = row0 + ty * 4 + i;
        if (r >= M) continue;
#pragma unroll
        for (int j = 0; j < 4; ++j) {
            int c = col0 + tx * 4 + j;
            if (c >= N) continue;
            float v = acc[i][j] + (bias ? bias[c] : 0.f);
            if (RELU) v = fmaxf(v, 0.f);
            C[(long long)r * ldc + c] = v;
        }
    }
}

// one wave per (node, head): a_src/a_dst dots
__global__ void attn_coef_kernel(const float* __restrict__ hbuf,
                                 const float* __restrict__ att_src,
                                 const float* __restrict__ att_dst,
                                 float* __restrict__ a_src,
                                 float* __restrict__ a_dst) {
    int gw = (blockIdx.x * blockDim.x + threadIdx.x) >> 6;
    int lane = threadIdx.x & 63;
    if (gw >= NN * 2) return;
    int n = gw >> 1, head = gw & 1;
    float hv = hbuf[n * 128 + head * 64 + lane];
    float vs = hv * att_src[head * 64 + lane];
    float vd = hv * att_dst[head * 64 + lane];
#pragma unroll
    for (int off = 32; off; off >>= 1) {
        vs += __shfl_down(vs, off);
        vd += __shfl_down(vd, off);
    }
    if (lane == 0) {
        a_src[n * 2 + head] = vs;
        a_dst[n * 2 + head] = vd;
    }
}

// ================= fused GAT aggregation (CSR gather) =================
// one wave per node; lane handles channels {2*lane, 2*lane+1}; head = lane>>5
template <int RELU>
__global__ void gat_agg_kernel(const int* __restrict__ row_ptr, const int* __restrict__ col,
                               const float* __restrict__ a_src, const float* __restrict__ a_dst,
                               const float* __restrict__ hbuf, const float* __restrict__ bias,
                               float* __restrict__ out) {
    int wid = (blockIdx.x * blockDim.x + threadIdx.x) >> 6;
    if (wid >= NN) return;
    int lane = threadIdx.x & 63;
    int head = lane >> 5;
    int n = wid;
    const float2* h2 = (const float2*)hbuf;

    float ad = a_dst[n * 2 + head];
    // self-loop (s = d = n)
    float e0 = a_src[n * 2 + head] + ad;
    e0 = e0 > 0.f ? e0 : 0.2f * e0;
    float w = expf(e0);
    float2 hv = h2[n * 64 + lane];
    float accx = w * hv.x, accy = w * hv.y, den = w;

    int rs = row_ptr[n], re = row_ptr[n + 1];
    for (int i = rs; i < re; ++i) {
        int s = col[i];
        float ee = a_src[s * 2 + head] + ad;
        ee = ee > 0.f ? ee : 0.2f * ee;
        float ww = expf(ee);
        float2 hs = h2[s * 64 + lane];
        accx += ww * hs.x;
        accy += ww * hs.y;
        den += ww;
    }
    float inv = 1.f / (den + 1e-16f);
    float2 b2 = ((const float2*)bias)[lane];
    float ox = accx * inv + b2.x;
    float oy = accy * inv + b2.y;
    if (RELU) { ox = fmaxf(ox, 0.f); oy = fmaxf(oy, 0.f); }
    float2 o;
    o.x = ox; o.y = oy;
    ((float2*)out)[n * 64 + lane] = o;
}

extern "C" void kernel_launch(void* const* d_in, const int* in_sizes, int n_in,
                              void* d_out, int out_size, void* d_ws, size_t ws_size,
                              hipStream_t stream) {
    const float* logits   = (const float*)d_in[0];
    const float* features = (const float*)d_in[1];
    const int*   ei       = (const int*)d_in[2];
    const float* W_feat   = (const float*)d_in[3];
    const float* b_feat   = (const float*)d_in[4];
    const float* W0       = (const float*)d_in[5];
    const float* att_src0 = (const float*)d_in[6];
    const float* att_dst0 = (const float*)d_in[7];
    const float* bias0    = (const float*)d_in[8];
    const float* W1       = (const float*)d_in[9];
    const float* att_src1 = (const float*)d_in[10];
    const float* att_dst1 = (const float*)d_in[11];
    const float* bias1    = (const float*)d_in[12];
    const float* W_out    = (const float*)d_in[13];
    const float* b_out    = (const float*)d_in[14];
    float* out = (float*)d_out;

    float* x0    = (float*)d_ws;            // N*168
    float* hbuf  = x0 + (size_t)NN * 168;   // N*128
    float* agg   = hbuf + (size_t)NN * 128; // N*128
    float* a_src = agg + (size_t)NN * 128;  // N*2
    float* a_dst = a_src + (size_t)NN * 2;  // N*2
    int* deg     = (int*)(a_dst + (size_t)NN * 2); // N
    int* row_ptr = deg + NN;                // N+1
    int* cursor  = row_ptr + NN + 1;        // N
    int* colbuf  = cursor + NN;             // E
    int* bsum    = colbuf + EE;             // NB_SCAN

    dim3 blk(256);

    // ---- CSR build (graph fixed for both layers) ----
    hipMemsetAsync(deg, 0, (size_t)NN * sizeof(int), stream);
    hist_kernel<<<dim3((EE + 255) / 256), blk, 0, stream>>>(ei, deg);
    scan_block_sums<<<dim3(NB_SCAN), blk, 0, stream>>>(deg, bsum);
    scan_bsum_kernel<<<dim3(1), blk, 0, stream>>>(bsum, NB_SCAN);
    scan_final_kernel<<<dim3(NB_SCAN), blk, 0, stream>>>(deg, bsum, row_ptr, cursor);
    scatter_kernel<<<dim3((EE + 255) / 256), blk, 0, stream>>>(ei, cursor, colbuf);

    // ---- input assembly ----
    copy_logits_kernel<<<dim3((NN * 40 + 255) / 256), blk, 0, stream>>>(logits, x0);
    {
        dim3 grid(2, (NN + 63) / 64);
        gemm_kernel<0><<<grid, blk, 0, stream>>>(features, 256, W_feat, 128, x0 + 40, 168,
                                                 b_feat, NN, 128, 256);
    }

    // ---- GAT layer 0 ----
    {
        dim3 grid(2, (NN + 63) / 64);
        gemm_kernel<0><<<grid, blk, 0, stream>>>(x0, 168, W0, 128, hbuf, 128,
                                                 (const float*)nullptr, NN, 128, 168);
    }
    attn_coef_kernel<<<dim3((NN * 2 * 64 + 255) / 256), blk, 0, stream>>>(hbuf, att_src0, att_dst0, a_src, a_dst);
    gat_agg_kernel<1><<<dim3((NN + 3) / 4), blk, 0, stream>>>(row_ptr, colbuf, a_src, a_dst,
                                                              hbuf, bias0, agg);

    // ---- GAT layer 1 ----
    {
        dim3 grid(2, (NN + 63) / 64);
        gemm_kernel<0><<<grid, blk, 0, stream>>>(agg, 128, W1, 128, hbuf, 128,
                                                 (const float*)nullptr, NN, 128, 128);
    }
    attn_coef_kernel<<<dim3((NN * 2 * 64 + 255) / 256), blk, 0, stream>>>(hbuf, att_src1, att_dst1, a_src, a_dst);
    gat_agg_kernel<0><<<dim3((NN + 3) / 4), blk, 0, stream>>>(row_ptr, colbuf, a_src, a_dst,
                                                              hbuf, bias1, agg);

    // ---- output projection ----
    {
        dim3 grid(1, (NN + 63) / 64);
        gemm_kernel<0><<<grid, blk, 0, stream>>>(agg, 128, W_out, 40, out, 40,
                                                 b_out, NN, 40, 128);
    }
}

// Round 3
// 913.919 us; speedup vs baseline: 2.4515x; 1.2106x over previous
//
#include <hip/hip_runtime.h>

#define NN 100000
#define EE 1600000
#define NB_SCAN ((NN + 1023) / 1024)

static __device__ inline unsigned short f2bf(float f) {
    unsigned int u = __float_as_uint(f);
    u += 0x7FFFu + ((u >> 16) & 1u);
    return (unsigned short)(u >> 16);
}

// ================= CSR build =================
__global__ void hist_kernel(const int* __restrict__ ei, int* __restrict__ deg) {
    int e = blockIdx.x * blockDim.x + threadIdx.x;
    if (e < EE) atomicAdd(&deg[ei[EE + e]], 1);
}

__global__ void scan_block_sums(const int* __restrict__ deg, int* __restrict__ bsum) {
    __shared__ int sdata[256];
    int base = blockIdx.x * 1024;
    int t = threadIdx.x;
    int s = 0;
#pragma unroll
    for (int i = 0; i < 4; ++i) {
        int idx = base + t * 4 + i;
        if (idx < NN) s += deg[idx];
    }
    sdata[t] = s;
    __syncthreads();
    for (int off = 128; off; off >>= 1) {
        if (t < off) sdata[t] += sdata[t + off];
        __syncthreads();
    }
    if (t == 0) bsum[blockIdx.x] = sdata[0];
}

__global__ void scan_bsum_kernel(int* __restrict__ bsum, int nb) {
    if (threadIdx.x == 0 && blockIdx.x == 0) {
        int acc = 0;
        for (int i = 0; i < nb; ++i) { int v = bsum[i]; bsum[i] = acc; acc += v; }
    }
}

__global__ void scan_final_kernel(const int* __restrict__ deg, const int* __restrict__ bsum,
                                  int* __restrict__ row_ptr, int* __restrict__ cursor) {
    __shared__ int ssum[256];
    int base = blockIdx.x * 1024;
    int t = threadIdx.x;
    int loc[4];
    int s = 0;
#pragma unroll
    for (int i = 0; i < 4; ++i) {
        int idx = base + t * 4 + i;
        loc[i] = (idx < NN) ? deg[idx] : 0;
        s += loc[i];
    }
    ssum[t] = s;
    __syncthreads();
    for (int off = 1; off < 256; off <<= 1) {
        int v = (t >= off) ? ssum[t - off] : 0;
        __syncthreads();
        ssum[t] += v;
        __syncthreads();
    }
    int excl = ssum[t] - s + bsum[blockIdx.x];
#pragma unroll
    for (int i = 0; i < 4; ++i) {
        int idx = base + t * 4 + i;
        if (idx < NN) {
            row_ptr[idx] = excl;
            cursor[idx] = excl;
            excl += loc[i];
        }
    }
    if (blockIdx.x == 0 && t == 0) row_ptr[NN] = EE;
}

__global__ void scatter_kernel(const int* __restrict__ ei, int* __restrict__ cursor,
                               int* __restrict__ col) {
    int e = blockIdx.x * blockDim.x + threadIdx.x;
    if (e < EE) {
        int d = ei[EE + e];
        int pos = atomicAdd(&cursor[d], 1);
        col[pos] = ei[e];
    }
}

// ================= small prep =================
__global__ void copy_logits_kernel(const float* __restrict__ logits, float* __restrict__ x) {
    int idx = blockIdx.x * blockDim.x + threadIdx.x;
    if (idx < NN * 10) {
        int n = idx / 10, q = idx - n * 10;
        *(float4*)(x + (long long)n * 168 + q * 4) = ((const float4*)logits)[idx];
    }
}

__global__ void pad_b_kernel(const float* __restrict__ src, int K, int N,
                             float* __restrict__ dst, int KP) {
    int idx = blockIdx.x * blockDim.x + threadIdx.x;
    if (idx < KP * 128) {
        int k = idx >> 7, c = idx & 127;
        dst[idx] = (k < K && c < N) ? src[k * N + c] : 0.f;
    }
}

// ================= fast f32 GEMM: C[M,128] = A[M,K] @ Bpad[KP,128] =================
// BM=128, BN=128, BK=32; 256 threads, 8x8 per thread.
// ATTN: fused a_src/a_dst row-dots via shfl.  OUTBF16: write bf16-packed h.
template <int ATTN, int OUTBF16>
__global__ __launch_bounds__(256, 2) void gemm128_kernel(
    const float* __restrict__ A, int lda, int K,
    const float* __restrict__ B, int KP,
    void* __restrict__ Cout, int ldc, int Nact,
    const float* __restrict__ bias,
    const float* __restrict__ att_src, const float* __restrict__ att_dst,
    float* __restrict__ a_src, float* __restrict__ a_dst, int M)
{
    __shared__ float As[32][132];   // transposed: As[k][row], stride 132 (bank-safe)
    __shared__ float Bs[32][128];
    const int tid = threadIdx.x;
    const int tx = tid & 15, ty = tid >> 4;
    const int row0 = blockIdx.x * 128;
    const int arow = tid >> 3;   // 0..31
    const int akq  = tid & 7;    // k-quad 0..7
    float acc[8][8] = {};

    for (int k0 = 0; k0 < KP; k0 += 32) {
        // stage A with transpose
#pragma unroll
        for (int i = 0; i < 4; ++i) {
            int r = arow + 32 * i;
            int gr = row0 + r;
            int gk = k0 + akq * 4;
            float4 av = make_float4(0.f, 0.f, 0.f, 0.f);
            if (gr < M && gk < K)
                av = *(const float4*)(A + (long long)gr * lda + gk);
            As[akq * 4 + 0][r] = av.x;
            As[akq * 4 + 1][r] = av.y;
            As[akq * 4 + 2][r] = av.z;
            As[akq * 4 + 3][r] = av.w;
        }
        // stage B (contiguous, padded: no guards)
#pragma unroll
        for (int i = 0; i < 4; ++i) {
            int br = tid >> 3;
            int q = (tid & 7) + 8 * i;
            *(float4*)&Bs[br][q * 4] = *(const float4*)(B + (k0 + br) * 128 + q * 4);
        }
        __syncthreads();
#pragma unroll
        for (int kk = 0; kk < 32; ++kk) {
            float4 a0 = *(float4*)&As[kk][ty * 8];
            float4 a1 = *(float4*)&As[kk][ty * 8 + 4];
            float4 b0 = *(float4*)&Bs[kk][tx * 8];
            float4 b1 = *(float4*)&Bs[kk][tx * 8 + 4];
            float a[8] = {a0.x, a0.y, a0.z, a0.w, a1.x, a1.y, a1.z, a1.w};
            float b[8] = {b0.x, b0.y, b0.z, b0.w, b1.x, b1.y, b1.z, b1.w};
#pragma unroll
            for (int i2 = 0; i2 < 8; ++i2)
#pragma unroll
                for (int j = 0; j < 8; ++j) acc[i2][j] += a[i2] * b[j];
        }
        __syncthreads();
    }

    const int lane = tid & 63;
#pragma unroll
    for (int i = 0; i < 8; ++i) {
        int r = row0 + ty * 8 + i;
        bool rok = (r < M);
        if (ATTN) {
            // att_src/att_dst are [H][C] contiguous = indexed by global col
            float ps = 0.f, pd = 0.f;
#pragma unroll
            for (int j = 0; j < 8; ++j) {
                int c = tx * 8 + j;
                ps += acc[i][j] * att_src[c];
                pd += acc[i][j] * att_dst[c];
            }
#pragma unroll
            for (int off = 1; off < 8; off <<= 1) {
                ps += __shfl_xor(ps, off);
                pd += __shfl_xor(pd, off);
            }
            if (rok && (lane & 7) == 0) {
                int head = (lane >> 3) & 1;
                a_src[r * 2 + head] = ps;
                a_dst[r * 2 + head] = pd;
            }
        }
        if (!rok) continue;
        if (OUTBF16) {
            unsigned short* hb = (unsigned short*)Cout;
            unsigned int pk[4];
#pragma unroll
            for (int q = 0; q < 4; ++q) {
                unsigned int lo = f2bf(acc[i][2 * q]);
                unsigned int hi = f2bf(acc[i][2 * q + 1]);
                pk[q] = lo | (hi << 16);
            }
            *(uint4*)(hb + (long long)r * 128 + tx * 8) = make_uint4(pk[0], pk[1], pk[2], pk[3]);
        } else {
            float* C = (float*)Cout;
            if (tx * 8 < Nact) {
                float v[8];
#pragma unroll
                for (int j = 0; j < 8; ++j)
                    v[j] = acc[i][j] + (bias ? bias[tx * 8 + j] : 0.f);
                *(float4*)(C + (long long)r * ldc + tx * 8) = make_float4(v[0], v[1], v[2], v[3]);
                *(float4*)(C + (long long)r * ldc + tx * 8 + 4) = make_float4(v[4], v[5], v[6], v[7]);
            }
        }
    }
}

// ================= fused GAT aggregation (CSR gather, bf16 h) =================
// one wave per node; lane owns channels {2*lane, 2*lane+1}; head = lane>>5
template <int RELU>
__global__ void gat_agg_kernel(const int* __restrict__ row_ptr, const int* __restrict__ col,
                               const float* __restrict__ a_src, const float* __restrict__ a_dst,
                               const unsigned short* __restrict__ hb,
                               const float* __restrict__ bias, float* __restrict__ out) {
    int wid = (blockIdx.x * 256 + threadIdx.x) >> 6;
    if (wid >= NN) return;
    int lane = threadIdx.x & 63;
    int head = lane >> 5;
    const unsigned int* h2 = (const unsigned int*)hb;

    float ad = a_dst[wid * 2 + head];
    float e0 = a_src[wid * 2 + head] + ad;           // self loop
    e0 = e0 > 0.f ? e0 : 0.2f * e0;
    float w = expf(e0);
    unsigned int hv = h2[wid * 64 + lane];
    float accx = w * __uint_as_float(hv << 16);
    float accy = w * __uint_as_float(hv & 0xFFFF0000u);
    float den = w;

    int rs = row_ptr[wid], re = row_ptr[wid + 1];
    for (int i = rs; i < re; ++i) {
        int s = col[i];
        float ee = a_src[s * 2 + head] + ad;
        ee = ee > 0.f ? ee : 0.2f * ee;
        float ww = expf(ee);
        unsigned int hs = h2[s * 64 + lane];
        accx += ww * __uint_as_float(hs << 16);
        accy += ww * __uint_as_float(hs & 0xFFFF0000u);
        den += ww;
    }
    float inv = 1.f / (den + 1e-16f);
    float2 b2 = ((const float2*)bias)[lane];
    float ox = accx * inv + b2.x;
    float oy = accy * inv + b2.y;
    if (RELU) { ox = fmaxf(ox, 0.f); oy = fmaxf(oy, 0.f); }
    ((float2*)out)[wid * 64 + lane] = make_float2(ox, oy);
}

extern "C" void kernel_launch(void* const* d_in, const int* in_sizes, int n_in,
                              void* d_out, int out_size, void* d_ws, size_t ws_size,
                              hipStream_t stream) {
    const float* logits   = (const float*)d_in[0];
    const float* features = (const float*)d_in[1];
    const int*   ei       = (const int*)d_in[2];
    const float* W_feat   = (const float*)d_in[3];
    const float* b_feat   = (const float*)d_in[4];
    const float* W0       = (const float*)d_in[5];
    const float* att_src0 = (const float*)d_in[6];
    const float* att_dst0 = (const float*)d_in[7];
    const float* bias0    = (const float*)d_in[8];
    const float* W1       = (const float*)d_in[9];
    const float* att_src1 = (const float*)d_in[10];
    const float* att_dst1 = (const float*)d_in[11];
    const float* bias1    = (const float*)d_in[12];
    const float* W_out    = (const float*)d_in[13];
    const float* b_out    = (const float*)d_in[14];
    float* out = (float*)d_out;

    float* x0     = (float*)d_ws;                       // NN*168
    float* agg    = x0 + (size_t)NN * 168;              // NN*128
    float* a_srcb = agg + (size_t)NN * 128;             // NN*2
    float* a_dstb = a_srcb + (size_t)NN * 2;            // NN*2
    unsigned short* hbuf = (unsigned short*)(a_dstb + (size_t)NN * 2); // NN*128 bf16
    float* Bp_feat = (float*)(hbuf + (size_t)NN * 128); // 256*128
    float* Bp0     = Bp_feat + 256 * 128;               // 192*128
    float* Bp1     = Bp0 + 192 * 128;                   // 128*128
    float* Bpout   = Bp1 + 128 * 128;                   // 128*128
    int* deg     = (int*)(Bpout + 128 * 128);           // NN
    int* row_ptr = deg + NN;                            // NN+1
    int* cursor  = row_ptr + NN + 1;                    // NN
    int* colbuf  = cursor + NN;                         // EE
    int* bsum    = colbuf + EE;                         // NB_SCAN

    dim3 blk(256);
    const int gemmGrid = (NN + 127) / 128;

    // ---- CSR build ----
    hipMemsetAsync(deg, 0, (size_t)NN * sizeof(int), stream);
    hist_kernel<<<dim3((EE + 255) / 256), blk, 0, stream>>>(ei, deg);
    scan_block_sums<<<dim3(NB_SCAN), blk, 0, stream>>>(deg, bsum);
    scan_bsum_kernel<<<dim3(1), blk, 0, stream>>>(bsum, NB_SCAN);
    scan_final_kernel<<<dim3(NB_SCAN), blk, 0, stream>>>(deg, bsum, row_ptr, cursor);
    scatter_kernel<<<dim3((EE + 255) / 256), blk, 0, stream>>>(ei, cursor, colbuf);

    // ---- pad B matrices (ldb=128, K padded to x32) ----
    pad_b_kernel<<<dim3((256 * 128 + 255) / 256), blk, 0, stream>>>(W_feat, 256, 128, Bp_feat, 256);
    pad_b_kernel<<<dim3((192 * 128 + 255) / 256), blk, 0, stream>>>(W0, 168, 128, Bp0, 192);
    pad_b_kernel<<<dim3((128 * 128 + 255) / 256), blk, 0, stream>>>(W1, 128, 128, Bp1, 128);
    pad_b_kernel<<<dim3((128 * 128 + 255) / 256), blk, 0, stream>>>(W_out, 128, 40, Bpout, 128);

    // ---- input assembly ----
    copy_logits_kernel<<<dim3((NN * 10 + 255) / 256), blk, 0, stream>>>(logits, x0);
    gemm128_kernel<0, 0><<<dim3(gemmGrid), blk, 0, stream>>>(
        features, 256, 256, Bp_feat, 256, x0 + 40, 168, 128, b_feat,
        nullptr, nullptr, nullptr, nullptr, NN);

    // ---- GAT layer 0 ----
    gemm128_kernel<1, 1><<<dim3(gemmGrid), blk, 0, stream>>>(
        x0, 168, 168, Bp0, 192, hbuf, 128, 128, nullptr,
        att_src0, att_dst0, a_srcb, a_dstb, NN);
    gat_agg_kernel<1><<<dim3((NN + 3) / 4), blk, 0, stream>>>(
        row_ptr, colbuf, a_srcb, a_dstb, hbuf, bias0, agg);

    // ---- GAT layer 1 ----
    gemm128_kernel<1, 1><<<dim3(gemmGrid), blk, 0, stream>>>(
        agg, 128, 128, Bp1, 128, hbuf, 128, 128, nullptr,
        att_src1, att_dst1, a_srcb, a_dstb, NN);
    gat_agg_kernel<0><<<dim3((NN + 3) / 4), blk, 0, stream>>>(
        row_ptr, colbuf, a_srcb, a_dstb, hbuf, bias1, agg);

    // ---- output projection ----
    gemm128_kernel<0, 0><<<dim3(gemmGrid), blk, 0, stream>>>(
        agg, 128, 128, Bpout, 128, out, 40, 40, b_out,
        nullptr, nullptr, nullptr, nullptr, NN);
}

// Round 4
// 864.761 us; speedup vs baseline: 2.5909x; 1.0568x over previous
//
#include <hip/hip_runtime.h>

#define NN 100000
#define EE 1600000
#define NB_SCAN ((NN + 1023) / 1024)

static __device__ inline unsigned short f2bf(float f) {
    unsigned int u = __float_as_uint(f);
    u += 0x7FFFu + ((u >> 16) & 1u);
    return (unsigned short)(u >> 16);
}

// ================= CSR build =================
__global__ void hist_kernel(const int* __restrict__ ei, int* __restrict__ deg) {
    int e = blockIdx.x * blockDim.x + threadIdx.x;
    if (e < EE) atomicAdd(&deg[ei[EE + e]], 1);
}

__global__ void scan_block_sums(const int* __restrict__ deg, int* __restrict__ bsum) {
    __shared__ int sdata[256];
    int base = blockIdx.x * 1024;
    int t = threadIdx.x;
    int s = 0;
#pragma unroll
    for (int i = 0; i < 4; ++i) {
        int idx = base + t * 4 + i;
        if (idx < NN) s += deg[idx];
    }
    sdata[t] = s;
    __syncthreads();
    for (int off = 128; off; off >>= 1) {
        if (t < off) sdata[t] += sdata[t + off];
        __syncthreads();
    }
    if (t == 0) bsum[blockIdx.x] = sdata[0];
}

__global__ void scan_bsum_kernel(int* __restrict__ bsum, int nb) {
    if (threadIdx.x == 0 && blockIdx.x == 0) {
        int acc = 0;
        for (int i = 0; i < nb; ++i) { int v = bsum[i]; bsum[i] = acc; acc += v; }
    }
}

__global__ void scan_final_kernel(const int* __restrict__ deg, const int* __restrict__ bsum,
                                  int* __restrict__ row_ptr, int* __restrict__ cursor) {
    __shared__ int ssum[256];
    int base = blockIdx.x * 1024;
    int t = threadIdx.x;
    int loc[4];
    int s = 0;
#pragma unroll
    for (int i = 0; i < 4; ++i) {
        int idx = base + t * 4 + i;
        loc[i] = (idx < NN) ? deg[idx] : 0;
        s += loc[i];
    }
    ssum[t] = s;
    __syncthreads();
    for (int off = 1; off < 256; off <<= 1) {
        int v = (t >= off) ? ssum[t - off] : 0;
        __syncthreads();
        ssum[t] += v;
        __syncthreads();
    }
    int excl = ssum[t] - s + bsum[blockIdx.x];
#pragma unroll
    for (int i = 0; i < 4; ++i) {
        int idx = base + t * 4 + i;
        if (idx < NN) {
            row_ptr[idx] = excl;
            cursor[idx] = excl;
            excl += loc[i];
        }
    }
    if (blockIdx.x == 0 && t == 0) row_ptr[NN] = EE;
}

__global__ void scatter_kernel(const int* __restrict__ ei, int* __restrict__ cursor,
                               int* __restrict__ col, int* __restrict__ perm) {
    int e = blockIdx.x * blockDim.x + threadIdx.x;
    if (e < EE) {
        int d = ei[EE + e];
        int pos = atomicAdd(&cursor[d], 1);
        col[pos] = ei[e];
        perm[e] = pos;
    }
}

// ================= small prep =================
__global__ void copy_logits_kernel(const float* __restrict__ logits, float* __restrict__ x) {
    int idx = blockIdx.x * blockDim.x + threadIdx.x;
    if (idx < NN * 10) {
        int n = idx / 10, q = idx - n * 10;
        *(float4*)(x + (long long)n * 168 + q * 4) = ((const float4*)logits)[idx];
    }
}

__global__ void pad_b_kernel(const float* __restrict__ src, int K, int N,
                             float* __restrict__ dst, int KP) {
    int idx = blockIdx.x * blockDim.x + threadIdx.x;
    if (idx < KP * 128) {
        int k = idx >> 7, c = idx & 127;
        dst[idx] = (k < K && c < N) ? src[k * N + c] : 0.f;
    }
}

// ================= fast f32 GEMM: C[M,128] = A[M,K] @ Bpad[KP,128] =================
template <int ATTN, int OUTBF16>
__global__ __launch_bounds__(256, 2) void gemm128_kernel(
    const float* __restrict__ A, int lda, int K,
    const float* __restrict__ B, int KP,
    void* __restrict__ Cout, int ldc, int Nact,
    const float* __restrict__ bias,
    const float* __restrict__ att_src, const float* __restrict__ att_dst,
    float* __restrict__ a_src, float* __restrict__ a_dst, int M)
{
    __shared__ float As[32][132];
    __shared__ float Bs[32][128];
    const int tid = threadIdx.x;
    const int tx = tid & 15, ty = tid >> 4;
    const int row0 = blockIdx.x * 128;
    const int arow = tid >> 3;
    const int akq  = tid & 7;
    float acc[8][8] = {};

    for (int k0 = 0; k0 < KP; k0 += 32) {
#pragma unroll
        for (int i = 0; i < 4; ++i) {
            int r = arow + 32 * i;
            int gr = row0 + r;
            int gk = k0 + akq * 4;
            float4 av = make_float4(0.f, 0.f, 0.f, 0.f);
            if (gr < M && gk < K)
                av = *(const float4*)(A + (long long)gr * lda + gk);
            As[akq * 4 + 0][r] = av.x;
            As[akq * 4 + 1][r] = av.y;
            As[akq * 4 + 2][r] = av.z;
            As[akq * 4 + 3][r] = av.w;
        }
#pragma unroll
        for (int i = 0; i < 4; ++i) {
            int br = tid >> 3;
            int q = (tid & 7) + 8 * i;
            *(float4*)&Bs[br][q * 4] = *(const float4*)(B + (k0 + br) * 128 + q * 4);
        }
        __syncthreads();
#pragma unroll
        for (int kk = 0; kk < 32; ++kk) {
            float4 a0 = *(float4*)&As[kk][ty * 8];
            float4 a1 = *(float4*)&As[kk][ty * 8 + 4];
            float4 b0 = *(float4*)&Bs[kk][tx * 8];
            float4 b1 = *(float4*)&Bs[kk][tx * 8 + 4];
            float a[8] = {a0.x, a0.y, a0.z, a0.w, a1.x, a1.y, a1.z, a1.w};
            float b[8] = {b0.x, b0.y, b0.z, b0.w, b1.x, b1.y, b1.z, b1.w};
#pragma unroll
            for (int i2 = 0; i2 < 8; ++i2)
#pragma unroll
                for (int j = 0; j < 8; ++j) acc[i2][j] += a[i2] * b[j];
        }
        __syncthreads();
    }

    const int lane = tid & 63;
#pragma unroll
    for (int i = 0; i < 8; ++i) {
        int r = row0 + ty * 8 + i;
        bool rok = (r < M);
        if (ATTN) {
            float ps = 0.f, pd = 0.f;
#pragma unroll
            for (int j = 0; j < 8; ++j) {
                int c = tx * 8 + j;
                ps += acc[i][j] * att_src[c];
                pd += acc[i][j] * att_dst[c];
            }
#pragma unroll
            for (int off = 1; off < 8; off <<= 1) {
                ps += __shfl_xor(ps, off);
                pd += __shfl_xor(pd, off);
            }
            if (rok && (lane & 7) == 0) {
                int head = (lane >> 3) & 1;
                a_src[r * 2 + head] = ps;
                a_dst[r * 2 + head] = pd;
            }
        }
        if (!rok) continue;
        if (OUTBF16) {
            unsigned short* hb = (unsigned short*)Cout;
            unsigned int pk[4];
#pragma unroll
            for (int q = 0; q < 4; ++q) {
                unsigned int lo = f2bf(acc[i][2 * q]);
                unsigned int hi = f2bf(acc[i][2 * q + 1]);
                pk[q] = lo | (hi << 16);
            }
            *(uint4*)(hb + (long long)r * 128 + tx * 8) = make_uint4(pk[0], pk[1], pk[2], pk[3]);
        } else {
            float* C = (float*)Cout;
            if (tx * 8 < Nact) {
                float v[8];
#pragma unroll
                for (int j = 0; j < 8; ++j)
                    v[j] = acc[i][j] + (bias ? bias[tx * 8 + j] : 0.f);
                *(float4*)(C + (long long)r * ldc + tx * 8) = make_float4(v[0], v[1], v[2], v[3]);
                *(float4*)(C + (long long)r * ldc + tx * 8 + 4) = make_float4(v[4], v[5], v[6], v[7]);
            }
        }
    }
}

// ================= per-edge weights (edge-parallel, once per edge-head) =================
__global__ void edge_w_kernel(const int* __restrict__ ei,
                              const float* __restrict__ a_src,
                              const float* __restrict__ a_dst,
                              const int* __restrict__ perm,
                              float* __restrict__ w0, float* __restrict__ w1) {
    int e = blockIdx.x * blockDim.x + threadIdx.x;
    if (e >= EE) return;
    int s = ei[e], d = ei[EE + e];
    float2 as = ((const float2*)a_src)[s];
    float2 ad = ((const float2*)a_dst)[d];
    float e0 = as.x + ad.x;
    float e1 = as.y + ad.y;
    e0 = e0 > 0.f ? e0 : 0.2f * e0;
    e1 = e1 > 0.f ? e1 : 0.2f * e1;
    int p = perm[e];
    w0[p] = expf(e0);
    w1[p] = expf(e1);
}

// ================= fused GAT aggregation (CSR gather, bf16 h, precomputed w) ========
// one wave per node; lane owns channels {2*lane, 2*lane+1}; head = lane>>5
template <int RELU>
__global__ void gat_agg_kernel(const int* __restrict__ row_ptr, const int* __restrict__ col,
                               const float* __restrict__ wb,
                               const float* __restrict__ a_src, const float* __restrict__ a_dst,
                               const unsigned short* __restrict__ hb,
                               const float* __restrict__ bias, float* __restrict__ out) {
    int wid = (blockIdx.x * 256 + threadIdx.x) >> 6;
    if (wid >= NN) return;
    int lane = threadIdx.x & 63;
    int head = lane >> 5;
    const unsigned int* h2 = (const unsigned int*)hb;
    const float* wsel = wb + (size_t)head * EE;

    // self loop (s = d = n), computed inline
    float e0 = a_src[wid * 2 + head] + a_dst[wid * 2 + head];
    e0 = e0 > 0.f ? e0 : 0.2f * e0;
    float w = expf(e0);
    unsigned int hv = h2[wid * 64 + lane];
    float accx = w * __uint_as_float(hv << 16);
    float accy = w * __uint_as_float(hv & 0xFFFF0000u);
    float den = w;

    int rs = row_ptr[wid], re = row_ptr[wid + 1];
    int i = rs;
    for (; i + 2 <= re; i += 2) {
        int s0 = col[i], s1 = col[i + 1];
        float ww0 = wsel[i], ww1 = wsel[i + 1];
        unsigned int hs0 = h2[s0 * 64 + lane];
        unsigned int hs1 = h2[s1 * 64 + lane];
        accx += ww0 * __uint_as_float(hs0 << 16);
        accy += ww0 * __uint_as_float(hs0 & 0xFFFF0000u);
        den += ww0;
        accx += ww1 * __uint_as_float(hs1 << 16);
        accy += ww1 * __uint_as_float(hs1 & 0xFFFF0000u);
        den += ww1;
    }
    if (i < re) {
        int s0 = col[i];
        float ww0 = wsel[i];
        unsigned int hs0 = h2[s0 * 64 + lane];
        accx += ww0 * __uint_as_float(hs0 << 16);
        accy += ww0 * __uint_as_float(hs0 & 0xFFFF0000u);
        den += ww0;
    }
    float inv = 1.f / (den + 1e-16f);
    float2 b2 = ((const float2*)bias)[lane];
    float ox = accx * inv + b2.x;
    float oy = accy * inv + b2.y;
    if (RELU) { ox = fmaxf(ox, 0.f); oy = fmaxf(oy, 0.f); }
    ((float2*)out)[wid * 64 + lane] = make_float2(ox, oy);
}

extern "C" void kernel_launch(void* const* d_in, const int* in_sizes, int n_in,
                              void* d_out, int out_size, void* d_ws, size_t ws_size,
                              hipStream_t stream) {
    const float* logits   = (const float*)d_in[0];
    const float* features = (const float*)d_in[1];
    const int*   ei       = (const int*)d_in[2];
    const float* W_feat   = (const float*)d_in[3];
    const float* b_feat   = (const float*)d_in[4];
    const float* W0       = (const float*)d_in[5];
    const float* att_src0 = (const float*)d_in[6];
    const float* att_dst0 = (const float*)d_in[7];
    const float* bias0    = (const float*)d_in[8];
    const float* W1       = (const float*)d_in[9];
    const float* att_src1 = (const float*)d_in[10];
    const float* att_dst1 = (const float*)d_in[11];
    const float* bias1    = (const float*)d_in[12];
    const float* W_out    = (const float*)d_in[13];
    const float* b_out    = (const float*)d_in[14];
    float* out = (float*)d_out;

    float* x0     = (float*)d_ws;                       // NN*168 (dead after L0 gemm)
    float* wbuf   = x0;                                 // 2*EE floats, aliases dead x0
    float* agg    = x0 + (size_t)NN * 168;              // NN*128
    float* a_srcb = agg + (size_t)NN * 128;             // NN*2
    float* a_dstb = a_srcb + (size_t)NN * 2;            // NN*2
    unsigned short* hbuf = (unsigned short*)(a_dstb + (size_t)NN * 2); // NN*128 bf16
    float* Bp_feat = (float*)(hbuf + (size_t)NN * 128); // 256*128
    float* Bp0     = Bp_feat + 256 * 128;               // 192*128
    float* Bp1     = Bp0 + 192 * 128;                   // 128*128
    float* Bpout   = Bp1 + 128 * 128;                   // 128*128
    int* deg     = (int*)(Bpout + 128 * 128);           // NN
    int* row_ptr = deg + NN;                            // NN+1
    int* cursor  = row_ptr + NN + 1;                    // NN
    int* colbuf  = cursor + NN;                         // EE
    int* perm    = colbuf + EE;                         // EE
    int* bsum    = perm + EE;                           // NB_SCAN

    dim3 blk(256);
    const int gemmGrid = (NN + 127) / 128;
    const int edgeGrid = (EE + 255) / 256;

    // ---- CSR build ----
    hipMemsetAsync(deg, 0, (size_t)NN * sizeof(int), stream);
    hist_kernel<<<dim3(edgeGrid), blk, 0, stream>>>(ei, deg);
    scan_block_sums<<<dim3(NB_SCAN), blk, 0, stream>>>(deg, bsum);
    scan_bsum_kernel<<<dim3(1), blk, 0, stream>>>(bsum, NB_SCAN);
    scan_final_kernel<<<dim3(NB_SCAN), blk, 0, stream>>>(deg, bsum, row_ptr, cursor);
    scatter_kernel<<<dim3(edgeGrid), blk, 0, stream>>>(ei, cursor, colbuf, perm);

    // ---- pad B matrices ----
    pad_b_kernel<<<dim3((256 * 128 + 255) / 256), blk, 0, stream>>>(W_feat, 256, 128, Bp_feat, 256);
    pad_b_kernel<<<dim3((192 * 128 + 255) / 256), blk, 0, stream>>>(W0, 168, 128, Bp0, 192);
    pad_b_kernel<<<dim3((128 * 128 + 255) / 256), blk, 0, stream>>>(W1, 128, 128, Bp1, 128);
    pad_b_kernel<<<dim3((128 * 128 + 255) / 256), blk, 0, stream>>>(W_out, 128, 40, Bpout, 128);

    // ---- input assembly ----
    copy_logits_kernel<<<dim3((NN * 10 + 255) / 256), blk, 0, stream>>>(logits, x0);
    gemm128_kernel<0, 0><<<dim3(gemmGrid), blk, 0, stream>>>(
        features, 256, 256, Bp_feat, 256, x0 + 40, 168, 128, b_feat,
        nullptr, nullptr, nullptr, nullptr, NN);

    // ---- GAT layer 0 ----
    gemm128_kernel<1, 1><<<dim3(gemmGrid), blk, 0, stream>>>(
        x0, 168, 168, Bp0, 192, hbuf, 128, 128, nullptr,
        att_src0, att_dst0, a_srcb, a_dstb, NN);
    // x0 is now dead; wbuf (aliasing x0) becomes live
    edge_w_kernel<<<dim3(edgeGrid), blk, 0, stream>>>(ei, a_srcb, a_dstb, perm, wbuf, wbuf + EE);
    gat_agg_kernel<1><<<dim3((NN + 3) / 4), blk, 0, stream>>>(
        row_ptr, colbuf, wbuf, a_srcb, a_dstb, hbuf, bias0, agg);

    // ---- GAT layer 1 ----
    gemm128_kernel<1, 1><<<dim3(gemmGrid), blk, 0, stream>>>(
        agg, 128, 128, Bp1, 128, hbuf, 128, 128, nullptr,
        att_src1, att_dst1, a_srcb, a_dstb, NN);
    edge_w_kernel<<<dim3(edgeGrid), blk, 0, stream>>>(ei, a_srcb, a_dstb, perm, wbuf, wbuf + EE);
    gat_agg_kernel<0><<<dim3((NN + 3) / 4), blk, 0, stream>>>(
        row_ptr, colbuf, wbuf, a_srcb, a_dstb, hbuf, bias1, agg);

    // ---- output projection ----
    gemm128_kernel<0, 0><<<dim3(gemmGrid), blk, 0, stream>>>(
        agg, 128, 128, Bpout, 128, out, 40, 40, b_out,
        nullptr, nullptr, nullptr, nullptr, NN);
}

// Round 5
// 676.480 us; speedup vs baseline: 3.3120x; 1.2783x over previous
//
#include <hip/hip_runtime.h>

#define NN 100000
#define EE 1600000
#define NB_SCAN ((NN + 1023) / 1024)

typedef __attribute__((ext_vector_type(8))) short short8_t;
typedef __attribute__((ext_vector_type(4))) float f32x4;

static __device__ inline unsigned short f2bf(float f) {
    unsigned int u = __float_as_uint(f);
    u += 0x7FFFu + ((u >> 16) & 1u);
    return (unsigned short)(u >> 16);
}
static __device__ inline float bf2f(unsigned short h) {
    return __uint_as_float(((unsigned int)h) << 16);
}

// ================= CSR build =================
__global__ void hist_kernel(const int* __restrict__ ei, int* __restrict__ deg) {
    int e = blockIdx.x * blockDim.x + threadIdx.x;
    if (e < EE) atomicAdd(&deg[ei[EE + e]], 1);
}

__global__ void scan_block_sums(const int* __restrict__ deg, int* __restrict__ bsum) {
    __shared__ int sdata[256];
    int base = blockIdx.x * 1024;
    int t = threadIdx.x;
    int s = 0;
#pragma unroll
    for (int i = 0; i < 4; ++i) {
        int idx = base + t * 4 + i;
        if (idx < NN) s += deg[idx];
    }
    sdata[t] = s;
    __syncthreads();
    for (int off = 128; off; off >>= 1) {
        if (t < off) sdata[t] += sdata[t + off];
        __syncthreads();
    }
    if (t == 0) bsum[blockIdx.x] = sdata[0];
}

__global__ void scan_bsum_kernel(int* __restrict__ bsum, int nb) {
    if (threadIdx.x == 0 && blockIdx.x == 0) {
        int acc = 0;
        for (int i = 0; i < nb; ++i) { int v = bsum[i]; bsum[i] = acc; acc += v; }
    }
}

__global__ void scan_final_kernel(const int* __restrict__ deg, const int* __restrict__ bsum,
                                  int* __restrict__ row_ptr, int* __restrict__ cursor) {
    __shared__ int ssum[256];
    int base = blockIdx.x * 1024;
    int t = threadIdx.x;
    int loc[4];
    int s = 0;
#pragma unroll
    for (int i = 0; i < 4; ++i) {
        int idx = base + t * 4 + i;
        loc[i] = (idx < NN) ? deg[idx] : 0;
        s += loc[i];
    }
    ssum[t] = s;
    __syncthreads();
    for (int off = 1; off < 256; off <<= 1) {
        int v = (t >= off) ? ssum[t - off] : 0;
        __syncthreads();
        ssum[t] += v;
        __syncthreads();
    }
    int excl = ssum[t] - s + bsum[blockIdx.x];
#pragma unroll
    for (int i = 0; i < 4; ++i) {
        int idx = base + t * 4 + i;
        if (idx < NN) {
            row_ptr[idx] = excl;
            cursor[idx] = excl;
            excl += loc[i];
        }
    }
    if (blockIdx.x == 0 && t == 0) row_ptr[NN] = EE;
}

__global__ void scatter_kernel(const int* __restrict__ ei, int* __restrict__ cursor,
                               int* __restrict__ col, int* __restrict__ perm) {
    int e = blockIdx.x * blockDim.x + threadIdx.x;
    if (e < EE) {
        int d = ei[EE + e];
        int pos = atomicAdd(&cursor[d], 1);
        col[pos] = ei[e];
        perm[e] = pos;
    }
}

// ================= small prep =================
__global__ void copy_logits_kernel(const float* __restrict__ logits, float* __restrict__ x) {
    int idx = blockIdx.x * blockDim.x + threadIdx.x;
    if (idx < NN * 10) {
        int n = idx / 10, q = idx - n * 10;
        *(float4*)(x + (long long)n * 168 + q * 4) = ((const float4*)logits)[idx];
    }
}

// W[K][N] f32 -> BT_hi/BT_lo[128][KP] bf16 (transposed, split, zero-padded)
__global__ void bsplit_kernel(const float* __restrict__ W, int K, int N,
                              unsigned short* __restrict__ BThi,
                              unsigned short* __restrict__ BTlo, int KP) {
    int k = blockIdx.x * 256 + threadIdx.x;
    int col = blockIdx.y;
    if (k >= KP) return;
    float v = (k < K && col < N) ? W[(size_t)k * N + col] : 0.f;
    unsigned short hi = f2bf(v);
    unsigned short lo = f2bf(v - bf2f(hi));
    BThi[(size_t)col * KP + k] = hi;
    BTlo[(size_t)col * KP + k] = lo;
}

// ================= split-bf16 MFMA GEMM: C[M,128] = A[M,K] @ B ===================
// BM=64, BN=128, BK=32. 256 threads = 4 waves; wave w: rows (w&1)*32..+32, cols (w>>1)*64..+64.
// A: f32 in global, split to bf16 hi/lo on the fly. B: pre-split BT planes [128][KP].
#define AHI 0
#define ALO 2048
#define BHI 4096
#define BLO 8192
template <int OUTBF16>
__global__ __launch_bounds__(256) void mfma_gemm_kernel(
    const float* __restrict__ A, int lda, int K, int M,
    const unsigned short* __restrict__ BThi, const unsigned short* __restrict__ BTlo, int KP,
    void* __restrict__ Cout, int ldc, int Nact, const float* __restrict__ bias)
{
    __shared__ __align__(16) unsigned short lds[12288];
    const int t = threadIdx.x;
    const int w = t >> 6, lane = t & 63;
    const int row0 = blockIdx.x * 64;
    const int rbase = (w & 1) * 32;
    const int cbase = (w >> 1) * 64;

    f32x4 acc[2][4];
#pragma unroll
    for (int i = 0; i < 2; ++i)
#pragma unroll
        for (int j = 0; j < 4; ++j) acc[i][j] = (f32x4){0.f, 0.f, 0.f, 0.f};

    const int arow = t >> 2;     // 0..63
    const int aslot = t & 3;     // 0..3
    const bool rowok = (row0 + arow) < M;
    const float* Arow = A + (size_t)(row0 + arow) * lda;
    const int aoff = arow * 32 + (((aslot ^ ((arow >> 1) & 3))) << 3);

    for (int k0 = 0; k0 < KP; k0 += 32) {
        // ---- stage A: load 8 f32, split to bf16 hi/lo, swizzled LDS write ----
        {
            int gk = k0 + aslot * 8;
            float a[8];
            if (rowok && gk + 8 <= K) {
                float4 v0 = *(const float4*)(Arow + gk);
                float4 v1 = *(const float4*)(Arow + gk + 4);
                a[0] = v0.x; a[1] = v0.y; a[2] = v0.z; a[3] = v0.w;
                a[4] = v1.x; a[5] = v1.y; a[6] = v1.z; a[7] = v1.w;
            } else {
#pragma unroll
                for (int j = 0; j < 8; ++j) a[j] = 0.f;
            }
            short8_t vh, vl;
#pragma unroll
            for (int j = 0; j < 8; ++j) {
                unsigned short hi = f2bf(a[j]);
                vh[j] = (short)hi;
                vl[j] = (short)f2bf(a[j] - bf2f(hi));
            }
            *(short8_t*)&lds[AHI + aoff] = vh;
            *(short8_t*)&lds[ALO + aoff] = vl;
        }
        // ---- stage B: copy bf16 planes, swizzled ----
#pragma unroll
        for (int i = 0; i < 2; ++i) {
            int idx = t + i * 256;
            int col = idx >> 2, slot = idx & 3;
            int bo = col * 32 + ((slot ^ ((col >> 1) & 3)) << 3);
            size_t gbo = (size_t)col * KP + k0 + slot * 8;
            *(short8_t*)&lds[BHI + bo] = *(const short8_t*)&BThi[gbo];
            *(short8_t*)&lds[BLO + bo] = *(const short8_t*)&BTlo[gbo];
        }
        __syncthreads();
        // ---- fragments + MFMA ----
        short8_t Ah[2], Al[2], Bh[4], Bl[4];
        const int fslot = lane >> 4;
#pragma unroll
        for (int rt = 0; rt < 2; ++rt) {
            int r = rbase + rt * 16 + (lane & 15);
            int off = r * 32 + ((fslot ^ ((r >> 1) & 3)) << 3);
            Ah[rt] = *(const short8_t*)&lds[AHI + off];
            Al[rt] = *(const short8_t*)&lds[ALO + off];
        }
#pragma unroll
        for (int ct = 0; ct < 4; ++ct) {
            int c = cbase + ct * 16 + (lane & 15);
            int off = c * 32 + ((fslot ^ ((c >> 1) & 3)) << 3);
            Bh[ct] = *(const short8_t*)&lds[BHI + off];
            Bl[ct] = *(const short8_t*)&lds[BLO + off];
        }
#pragma unroll
        for (int rt = 0; rt < 2; ++rt)
#pragma unroll
            for (int ct = 0; ct < 4; ++ct) {
                acc[rt][ct] = __builtin_amdgcn_mfma_f32_16x16x32_bf16(Ah[rt], Bh[ct], acc[rt][ct], 0, 0, 0);
                acc[rt][ct] = __builtin_amdgcn_mfma_f32_16x16x32_bf16(Ah[rt], Bl[ct], acc[rt][ct], 0, 0, 0);
                acc[rt][ct] = __builtin_amdgcn_mfma_f32_16x16x32_bf16(Al[rt], Bh[ct], acc[rt][ct], 0, 0, 0);
            }
        __syncthreads();
    }

    // ---- epilogue: D row = (lane>>4)*4+reg, col = lane&15 (within 16x16 tile) ----
#pragma unroll
    for (int rt = 0; rt < 2; ++rt) {
#pragma unroll
        for (int reg = 0; reg < 4; ++reg) {
            int r = row0 + rbase + rt * 16 + (lane >> 4) * 4 + reg;
            if (r >= M) continue;
#pragma unroll
            for (int ct = 0; ct < 4; ++ct) {
                int c = cbase + ct * 16 + (lane & 15);
                float v = acc[rt][ct][reg];
                if (OUTBF16) {
                    ((unsigned short*)Cout)[(size_t)r * 128 + c] = f2bf(v);
                } else {
                    if (c < Nact)
                        ((float*)Cout)[(size_t)r * ldc + c] = v + (bias ? bias[c] : 0.f);
                }
            }
        }
    }
}

// ================= attention coefficients from bf16 h =================
// one wave per node; lane owns channels {2*lane, 2*lane+1}; head = lane>>5
__global__ void attn_coef_bf16(const unsigned short* __restrict__ hb,
                               const float* __restrict__ att_src,
                               const float* __restrict__ att_dst,
                               float* __restrict__ a_src, float* __restrict__ a_dst) {
    int n = (blockIdx.x * 256 + threadIdx.x) >> 6;
    if (n >= NN) return;
    int lane = threadIdx.x & 63;
    unsigned int hv = ((const unsigned int*)hb)[n * 64 + lane];
    float hx = __uint_as_float(hv << 16);
    float hy = __uint_as_float(hv & 0xFFFF0000u);
    int c0 = lane * 2;
    float vs = hx * att_src[c0] + hy * att_src[c0 + 1];
    float vd = hx * att_dst[c0] + hy * att_dst[c0 + 1];
#pragma unroll
    for (int off = 1; off <= 16; off <<= 1) {
        vs += __shfl_xor(vs, off);
        vd += __shfl_xor(vd, off);
    }
    if ((lane & 31) == 0) {
        int head = lane >> 5;
        a_src[n * 2 + head] = vs;
        a_dst[n * 2 + head] = vd;
    }
}

// ================= per-edge weights =================
__global__ void edge_w_kernel(const int* __restrict__ ei,
                              const float* __restrict__ a_src,
                              const float* __restrict__ a_dst,
                              const int* __restrict__ perm,
                              float* __restrict__ w0, float* __restrict__ w1) {
    int e = blockIdx.x * blockDim.x + threadIdx.x;
    if (e >= EE) return;
    int s = ei[e], d = ei[EE + e];
    float2 as = ((const float2*)a_src)[s];
    float2 ad = ((const float2*)a_dst)[d];
    float e0 = as.x + ad.x;
    float e1 = as.y + ad.y;
    e0 = e0 > 0.f ? e0 : 0.2f * e0;
    e1 = e1 > 0.f ? e1 : 0.2f * e1;
    int p = perm[e];
    w0[p] = expf(e0);
    w1[p] = expf(e1);
}

// ================= fused GAT aggregation (CSR gather) =================
template <int RELU>
__global__ void gat_agg_kernel(const int* __restrict__ row_ptr, const int* __restrict__ col,
                               const float* __restrict__ wb,
                               const float* __restrict__ a_src, const float* __restrict__ a_dst,
                               const unsigned short* __restrict__ hb,
                               const float* __restrict__ bias, float* __restrict__ out) {
    int wid = (blockIdx.x * 256 + threadIdx.x) >> 6;
    if (wid >= NN) return;
    int lane = threadIdx.x & 63;
    int head = lane >> 5;
    const unsigned int* h2 = (const unsigned int*)hb;
    const float* wsel = wb + (size_t)head * EE;

    float e0 = a_src[wid * 2 + head] + a_dst[wid * 2 + head];
    e0 = e0 > 0.f ? e0 : 0.2f * e0;
    float w = expf(e0);
    unsigned int hv = h2[wid * 64 + lane];
    float accx = w * __uint_as_float(hv << 16);
    float accy = w * __uint_as_float(hv & 0xFFFF0000u);
    float den = w;

    int rs = row_ptr[wid], re = row_ptr[wid + 1];
    int i = rs;
    for (; i + 2 <= re; i += 2) {
        int s0 = col[i], s1 = col[i + 1];
        float ww0 = wsel[i], ww1 = wsel[i + 1];
        unsigned int hs0 = h2[s0 * 64 + lane];
        unsigned int hs1 = h2[s1 * 64 + lane];
        accx += ww0 * __uint_as_float(hs0 << 16);
        accy += ww0 * __uint_as_float(hs0 & 0xFFFF0000u);
        den += ww0;
        accx += ww1 * __uint_as_float(hs1 << 16);
        accy += ww1 * __uint_as_float(hs1 & 0xFFFF0000u);
        den += ww1;
    }
    if (i < re) {
        int s0 = col[i];
        float ww0 = wsel[i];
        unsigned int hs0 = h2[s0 * 64 + lane];
        accx += ww0 * __uint_as_float(hs0 << 16);
        accy += ww0 * __uint_as_float(hs0 & 0xFFFF0000u);
        den += ww0;
    }
    float inv = 1.f / (den + 1e-16f);
    float2 b2 = ((const float2*)bias)[lane];
    float ox = accx * inv + b2.x;
    float oy = accy * inv + b2.y;
    if (RELU) { ox = fmaxf(ox, 0.f); oy = fmaxf(oy, 0.f); }
    ((float2*)out)[wid * 64 + lane] = make_float2(ox, oy);
}

extern "C" void kernel_launch(void* const* d_in, const int* in_sizes, int n_in,
                              void* d_out, int out_size, void* d_ws, size_t ws_size,
                              hipStream_t stream) {
    const float* logits   = (const float*)d_in[0];
    const float* features = (const float*)d_in[1];
    const int*   ei       = (const int*)d_in[2];
    const float* W_feat   = (const float*)d_in[3];
    const float* b_feat   = (const float*)d_in[4];
    const float* W0       = (const float*)d_in[5];
    const float* att_src0 = (const float*)d_in[6];
    const float* att_dst0 = (const float*)d_in[7];
    const float* bias0    = (const float*)d_in[8];
    const float* W1       = (const float*)d_in[9];
    const float* att_src1 = (const float*)d_in[10];
    const float* att_dst1 = (const float*)d_in[11];
    const float* bias1    = (const float*)d_in[12];
    const float* W_out    = (const float*)d_in[13];
    const float* b_out    = (const float*)d_in[14];
    float* out = (float*)d_out;

    float* x0     = (float*)d_ws;                       // NN*168 (dead after L0 gemm)
    float* wbuf   = x0;                                 // 2*EE floats, aliases dead x0
    float* agg    = x0 + (size_t)NN * 168;              // NN*128
    float* a_srcb = agg + (size_t)NN * 128;             // NN*2
    float* a_dstb = a_srcb + (size_t)NN * 2;            // NN*2
    unsigned short* hbuf = (unsigned short*)(a_dstb + (size_t)NN * 2); // NN*128 bf16
    unsigned short* BThi_f = hbuf + (size_t)NN * 128;   // 128*256
    unsigned short* BTlo_f = BThi_f + 128 * 256;
    unsigned short* BThi_0 = BTlo_f + 128 * 256;        // 128*192
    unsigned short* BTlo_0 = BThi_0 + 128 * 192;
    unsigned short* BThi_1 = BTlo_0 + 128 * 192;        // 128*128
    unsigned short* BTlo_1 = BThi_1 + 128 * 128;
    unsigned short* BThi_o = BTlo_1 + 128 * 128;        // 128*128
    unsigned short* BTlo_o = BThi_o + 128 * 128;
    int* deg     = (int*)(BTlo_o + 128 * 128);          // NN
    int* row_ptr = deg + NN;                            // NN+1
    int* cursor  = row_ptr + NN + 1;                    // NN
    int* colbuf  = cursor + NN;                         // EE
    int* perm    = colbuf + EE;                         // EE
    int* bsum    = perm + EE;                           // NB_SCAN

    dim3 blk(256);
    const int gemmGrid = (NN + 63) / 64;
    const int edgeGrid = (EE + 255) / 256;
    const int nodeWaveGrid = (NN + 3) / 4;

    // ---- CSR build ----
    hipMemsetAsync(deg, 0, (size_t)NN * sizeof(int), stream);
    hist_kernel<<<dim3(edgeGrid), blk, 0, stream>>>(ei, deg);
    scan_block_sums<<<dim3(NB_SCAN), blk, 0, stream>>>(deg, bsum);
    scan_bsum_kernel<<<dim3(1), blk, 0, stream>>>(bsum, NB_SCAN);
    scan_final_kernel<<<dim3(NB_SCAN), blk, 0, stream>>>(deg, bsum, row_ptr, cursor);
    scatter_kernel<<<dim3(edgeGrid), blk, 0, stream>>>(ei, cursor, colbuf, perm);

    // ---- split/transpose weights ----
    bsplit_kernel<<<dim3(1, 128), blk, 0, stream>>>(W_feat, 256, 128, BThi_f, BTlo_f, 256);
    bsplit_kernel<<<dim3(1, 128), blk, 0, stream>>>(W0, 168, 128, BThi_0, BTlo_0, 192);
    bsplit_kernel<<<dim3(1, 128), blk, 0, stream>>>(W1, 128, 128, BThi_1, BTlo_1, 128);
    bsplit_kernel<<<dim3(1, 128), blk, 0, stream>>>(W_out, 128, 40, BThi_o, BTlo_o, 128);

    // ---- input assembly ----
    copy_logits_kernel<<<dim3((NN * 10 + 255) / 256), blk, 0, stream>>>(logits, x0);
    mfma_gemm_kernel<0><<<dim3(gemmGrid), blk, 0, stream>>>(
        features, 256, 256, NN, BThi_f, BTlo_f, 256, x0 + 40, 168, 128, b_feat);

    // ---- GAT layer 0 ----
    mfma_gemm_kernel<1><<<dim3(gemmGrid), blk, 0, stream>>>(
        x0, 168, 168, NN, BThi_0, BTlo_0, 192, hbuf, 128, 128, nullptr);
    attn_coef_bf16<<<dim3(nodeWaveGrid), blk, 0, stream>>>(hbuf, att_src0, att_dst0, a_srcb, a_dstb);
    // x0 is now dead; wbuf (aliasing x0) becomes live
    edge_w_kernel<<<dim3(edgeGrid), blk, 0, stream>>>(ei, a_srcb, a_dstb, perm, wbuf, wbuf + EE);
    gat_agg_kernel<1><<<dim3(nodeWaveGrid), blk, 0, stream>>>(
        row_ptr, colbuf, wbuf, a_srcb, a_dstb, hbuf, bias0, agg);

    // ---- GAT layer 1 ----
    mfma_gemm_kernel<1><<<dim3(gemmGrid), blk, 0, stream>>>(
        agg, 128, 128, NN, BThi_1, BTlo_1, 128, hbuf, 128, 128, nullptr);
    attn_coef_bf16<<<dim3(nodeWaveGrid), blk, 0, stream>>>(hbuf, att_src1, att_dst1, a_srcb, a_dstb);
    edge_w_kernel<<<dim3(edgeGrid), blk, 0, stream>>>(ei, a_srcb, a_dstb, perm, wbuf, wbuf + EE);
    gat_agg_kernel<0><<<dim3(nodeWaveGrid), blk, 0, stream>>>(
        row_ptr, colbuf, wbuf, a_srcb, a_dstb, hbuf, bias1, agg);

    // ---- output projection ----
    mfma_gemm_kernel<0><<<dim3(gemmGrid), blk, 0, stream>>>(
        agg, 128, 128, NN, BThi_o, BTlo_o, 128, out, 40, 40, b_out);
}